// Round 1
// baseline (119.598 us; speedup 1.0000x reference)
//
#include <hip/hip_runtime.h>

// NCC loss, fused single-pass:
//   per-thread: 4 columns, 5 running vertical sums (I, J, I2, J2, IJ) over a
//   9-row window; horizontal 9-sums computed per row from 3 aligned float4
//   loads per input via a running sum. Subtract-row recomputed from global
//   (L1/L2 hit) instead of a register/LDS ring.
// Grid: B images x 32 bands of 16 rows = 1024 blocks x 128 threads.
// Deterministic reduction: block partials -> d_ws, finish kernel -> d_out.

#define W 512
#define H 512
#define BH 16
#define NBANDS (H / BH)      // 32
#define NTHREADS 128         // 4 columns per thread -> 512 columns

__device__ __forceinline__ float4 ld4(const float* p) {
    return *reinterpret_cast<const float4*>(p);
}

template<bool ADD>
__device__ __forceinline__ void row_accum(const float* __restrict__ Ip,
                                          const float* __restrict__ Jp,
                                          int rowbase, int x0,
                                          float vs[5][4]) {
    const float4 zz = make_float4(0.f, 0.f, 0.f, 0.f);
    // Columns x0-4 .. x0+7 as three float4 chunks; edge chunks are either
    // fully in-bounds or fully OOB (W multiple of 4, x0 multiple of 4).
    float4 a0 = (x0 >= 4)     ? ld4(Ip + rowbase + x0 - 4) : zz;
    float4 a1 =                 ld4(Ip + rowbase + x0);
    float4 a2 = (x0 <= W - 8) ? ld4(Ip + rowbase + x0 + 4) : zz;
    float4 b0 = (x0 >= 4)     ? ld4(Jp + rowbase + x0 - 4) : zz;
    float4 b1 =                 ld4(Jp + rowbase + x0);
    float4 b2 = (x0 <= W - 8) ? ld4(Jp + rowbase + x0 + 4) : zz;

    float iv[12], jv[12];
    iv[0]=a0.x; iv[1]=a0.y; iv[2]=a0.z; iv[3]=a0.w;
    iv[4]=a1.x; iv[5]=a1.y; iv[6]=a1.z; iv[7]=a1.w;
    iv[8]=a2.x; iv[9]=a2.y; iv[10]=a2.z; iv[11]=a2.w;
    jv[0]=b0.x; jv[1]=b0.y; jv[2]=b0.z; jv[3]=b0.w;
    jv[4]=b1.x; jv[5]=b1.y; jv[6]=b1.z; jv[7]=b1.w;
    jv[8]=b2.x; jv[9]=b2.y; jv[10]=b2.z; jv[11]=b2.w;

    // Horizontal 9-window running sums for 4 output columns per quantity.
    auto doq = [&](int qi, auto f) {
        float p[12];
        #pragma unroll
        for (int k = 0; k < 12; ++k) p[k] = f(k);
        float t = p[0];
        #pragma unroll
        for (int k = 1; k < 9; ++k) t += p[k];
        if (ADD) vs[qi][0] += t; else vs[qi][0] -= t;
        #pragma unroll
        for (int c = 1; c < 4; ++c) {
            t += p[c + 8] - p[c - 1];
            if (ADD) vs[qi][c] += t; else vs[qi][c] -= t;
        }
    };
    doq(0, [&](int k) { return iv[k]; });
    doq(1, [&](int k) { return jv[k]; });
    doq(2, [&](int k) { return iv[k] * iv[k]; });
    doq(3, [&](int k) { return jv[k] * jv[k]; });
    doq(4, [&](int k) { return iv[k] * jv[k]; });
}

__global__ __launch_bounds__(NTHREADS)
void ncc_main(const float* __restrict__ I, const float* __restrict__ J,
              float* __restrict__ partials) {
    const int blk  = blockIdx.x;
    const int b    = blk / NBANDS;
    const int band = blk % NBANDS;
    const int y0   = band * BH;
    const float* Ip = I + (size_t)b * (H * W);
    const float* Jp = J + (size_t)b * (H * W);
    const int x0 = (int)threadIdx.x * 4;

    float vs[5][4];
    #pragma unroll
    for (int q = 0; q < 5; ++q)
        #pragma unroll
        for (int c = 0; c < 4; ++c) vs[q][c] = 0.f;

    // Prime the vertical window with rows y0-4 .. y0+3 (zero pad outside).
    #pragma unroll
    for (int dr = -4; dr < 4; ++dr) {
        int r = y0 + dr;
        if (r >= 0 && r < H) row_accum<true>(Ip, Jp, r * W, x0, vs);
    }

    float cc_acc = 0.f;
    const float inv81 = 1.f / 81.f;
    for (int y = y0; y < y0 + BH; ++y) {
        int ra = y + 4;
        if (ra < H) row_accum<true>(Ip, Jp, ra * W, x0, vs);
        // vs now holds box sums over rows [y-4, y+4] (clipped), cols +-4.
        #pragma unroll
        for (int c = 0; c < 4; ++c) {
            float Is = vs[0][c], Js = vs[1][c];
            float I2 = vs[2][c], J2 = vs[3][c], IJ = vs[4][c];
            float cross = IJ - Is * Js * inv81;
            float Ivar  = I2 - Is * Is * inv81;
            float Jvar  = J2 - Js * Js * inv81;
            cc_acc += cross * cross / (Ivar * Jvar + 1e-6f);
        }
        int rs = y - 4;  // drop row y-4 so next iter's window is [y-3, y+5]
        if (rs >= 0) row_accum<false>(Ip, Jp, rs * W, x0, vs);
    }

    // Block reduction: 2 waves.
    #pragma unroll
    for (int off = 32; off > 0; off >>= 1)
        cc_acc += __shfl_down(cc_acc, off, 64);
    __shared__ float wsum[NTHREADS / 64];
    if ((threadIdx.x & 63) == 0) wsum[threadIdx.x >> 6] = cc_acc;
    __syncthreads();
    if (threadIdx.x == 0) partials[blockIdx.x] = wsum[0] + wsum[1];
}

__global__ __launch_bounds__(256)
void ncc_finish(const float* __restrict__ partials, float* __restrict__ out,
                int n, float inv_total) {
    float v = 0.f;
    for (int i = threadIdx.x; i < n; i += blockDim.x) v += partials[i];
    #pragma unroll
    for (int off = 32; off > 0; off >>= 1)
        v += __shfl_down(v, off, 64);
    __shared__ float wsum[4];
    if ((threadIdx.x & 63) == 0) wsum[threadIdx.x >> 6] = v;
    __syncthreads();
    if (threadIdx.x == 0) {
        float t = wsum[0] + wsum[1] + wsum[2] + wsum[3];
        out[0] = 1.0f - t * inv_total;
    }
}

extern "C" void kernel_launch(void* const* d_in, const int* in_sizes, int n_in,
                              void* d_out, int out_size, void* d_ws, size_t ws_size,
                              hipStream_t stream) {
    const float* I = (const float*)d_in[0];   // predict
    const float* J = (const float*)d_in[1];   // target
    float* out = (float*)d_out;
    float* partials = (float*)d_ws;           // nblocks floats (4 KB)

    const int n = in_sizes[0];                // B*1*H*W
    const int B = n / (H * W);
    const int nblocks = B * NBANDS;

    ncc_main<<<nblocks, NTHREADS, 0, stream>>>(I, J, partials);
    ncc_finish<<<1, 256, 0, stream>>>(partials, out, nblocks, 1.0f / (float)n);
}

// Round 2
// 118.163 us; speedup vs baseline: 1.0121x; 1.0121x over previous
//
#include <hip/hip_runtime.h>

// NCC loss, fused single-pass. Round 2 changes vs R1:
//  - BH 16 -> 8: 2048 blocks (8 blocks/CU, 16 waves/CU) to fix the 18%
//    occupancy / latency-bound profile (R1: VALU 45%, HBM 19%).
//  - add-row and subtract-row loads issued together each iteration
//    (window kept as [y-4, y+3]; cc computed on vs+ha; then vs = win - hs).
//  - tree-shaped 9-sums to shorten dependent add chains.
// Deterministic reduction: block partials -> d_ws, finish kernel -> d_out.

#define W 512
#define H 512
#define BH 8
#define NBANDS (H / BH)      // 64
#define NTHREADS 128         // 4 columns per thread -> 512 columns

__device__ __forceinline__ float4 ld4(const float* p) {
    return *reinterpret_cast<const float4*>(p);
}

struct Row6 { float4 a0, a1, a2, b0, b1, b2; };

__device__ __forceinline__ Row6 load_row(const float* __restrict__ Ip,
                                         const float* __restrict__ Jp,
                                         int rowbase, int x0, bool valid) {
    const float4 zz = make_float4(0.f, 0.f, 0.f, 0.f);
    Row6 r;
    if (valid) {
        // Columns x0-4 .. x0+7 as three float4 chunks; edge chunks are either
        // fully in-bounds or fully OOB (W multiple of 4, x0 multiple of 4).
        r.a0 = (x0 >= 4)     ? ld4(Ip + rowbase + x0 - 4) : zz;
        r.a1 =                 ld4(Ip + rowbase + x0);
        r.a2 = (x0 <= W - 8) ? ld4(Ip + rowbase + x0 + 4) : zz;
        r.b0 = (x0 >= 4)     ? ld4(Jp + rowbase + x0 - 4) : zz;
        r.b1 =                 ld4(Jp + rowbase + x0);
        r.b2 = (x0 <= W - 8) ? ld4(Jp + rowbase + x0 + 4) : zz;
    } else {
        r.a0 = r.a1 = r.a2 = r.b0 = r.b1 = r.b2 = zz;
    }
    return r;
}

// Horizontal 9-window sums for 4 output columns x 5 quantities.
__device__ __forceinline__ void hsum(const Row6& r, float h[5][4]) {
    float iv[12], jv[12];
    iv[0]=r.a0.x; iv[1]=r.a0.y; iv[2]=r.a0.z; iv[3]=r.a0.w;
    iv[4]=r.a1.x; iv[5]=r.a1.y; iv[6]=r.a1.z; iv[7]=r.a1.w;
    iv[8]=r.a2.x; iv[9]=r.a2.y; iv[10]=r.a2.z; iv[11]=r.a2.w;
    jv[0]=r.b0.x; jv[1]=r.b0.y; jv[2]=r.b0.z; jv[3]=r.b0.w;
    jv[4]=r.b1.x; jv[5]=r.b1.y; jv[6]=r.b1.z; jv[7]=r.b1.w;
    jv[8]=r.b2.x; jv[9]=r.b2.y; jv[10]=r.b2.z; jv[11]=r.b2.w;

    auto doq = [&](int qi, auto f) {
        float p[12];
        #pragma unroll
        for (int k = 0; k < 12; ++k) p[k] = f(k);
        // Tree 9-sum for column 0, then rolling updates for columns 1..3.
        float s01 = p[0] + p[1], s23 = p[2] + p[3];
        float s45 = p[4] + p[5], s67 = p[6] + p[7];
        float t = ((s01 + s23) + (s45 + s67)) + p[8];
        h[qi][0] = t;
        t += p[9]  - p[0]; h[qi][1] = t;
        t += p[10] - p[1]; h[qi][2] = t;
        t += p[11] - p[2]; h[qi][3] = t;
    };
    doq(0, [&](int k) { return iv[k]; });
    doq(1, [&](int k) { return jv[k]; });
    doq(2, [&](int k) { return iv[k] * iv[k]; });
    doq(3, [&](int k) { return jv[k] * jv[k]; });
    doq(4, [&](int k) { return iv[k] * jv[k]; });
}

__global__ __launch_bounds__(NTHREADS)
void ncc_main(const float* __restrict__ I, const float* __restrict__ J,
              float* __restrict__ partials) {
    const int blk  = blockIdx.x;
    const int b    = blk / NBANDS;
    const int band = blk % NBANDS;
    const int y0   = band * BH;
    const float* Ip = I + (size_t)b * (H * W);
    const float* Jp = J + (size_t)b * (H * W);
    const int x0 = (int)threadIdx.x * 4;

    // vs holds the window over rows [y-4, y+3] entering each iteration.
    float vs[5][4];
    #pragma unroll
    for (int q = 0; q < 5; ++q)
        #pragma unroll
        for (int c = 0; c < 4; ++c) vs[q][c] = 0.f;

    // Prime with rows y0-4 .. y0+3 (zero pad outside).
    #pragma unroll
    for (int dr = -4; dr < 4; ++dr) {
        int r = y0 + dr;
        if (r >= 0 && r < H) {
            Row6 rw = load_row(Ip, Jp, r * W, x0, true);
            float hh[5][4];
            hsum(rw, hh);
            #pragma unroll
            for (int q = 0; q < 5; ++q)
                #pragma unroll
                for (int c = 0; c < 4; ++c) vs[q][c] += hh[q][c];
        }
    }

    float cc_acc = 0.f;
    const float inv81 = 1.f / 81.f;
    for (int y = y0; y < y0 + BH; ++y) {
        // Issue both rows' loads together (independent chains).
        Row6 ra = load_row(Ip, Jp, (y + 4) * W, x0, (y + 4) < H);
        Row6 rs = load_row(Ip, Jp, (y - 4) * W, x0, (y - 4) >= 0);
        float ha[5][4], hs[5][4];
        hsum(ra, ha);
        hsum(rs, hs);

        #pragma unroll
        for (int c = 0; c < 4; ++c) {
            float Is = vs[0][c] + ha[0][c];
            float Js = vs[1][c] + ha[1][c];
            float I2 = vs[2][c] + ha[2][c];
            float J2 = vs[3][c] + ha[3][c];
            float IJ = vs[4][c] + ha[4][c];
            float cross = IJ - Is * Js * inv81;
            float Ivar  = I2 - Is * Is * inv81;
            float Jvar  = J2 - Js * Js * inv81;
            cc_acc += cross * cross / (Ivar * Jvar + 1e-6f);
            // Slide window: [y-4, y+4] minus row y-4 -> [y-3, y+4].
            vs[0][c] = Is - hs[0][c];
            vs[1][c] = Js - hs[1][c];
            vs[2][c] = I2 - hs[2][c];
            vs[3][c] = J2 - hs[3][c];
            vs[4][c] = IJ - hs[4][c];
        }
    }

    // Block reduction: 2 waves.
    #pragma unroll
    for (int off = 32; off > 0; off >>= 1)
        cc_acc += __shfl_down(cc_acc, off, 64);
    __shared__ float wsum[NTHREADS / 64];
    if ((threadIdx.x & 63) == 0) wsum[threadIdx.x >> 6] = cc_acc;
    __syncthreads();
    if (threadIdx.x == 0) partials[blockIdx.x] = wsum[0] + wsum[1];
}

__global__ __launch_bounds__(256)
void ncc_finish(const float* __restrict__ partials, float* __restrict__ out,
                int n, float inv_total) {
    float v = 0.f;
    for (int i = threadIdx.x; i < n; i += blockDim.x) v += partials[i];
    #pragma unroll
    for (int off = 32; off > 0; off >>= 1)
        v += __shfl_down(v, off, 64);
    __shared__ float wsum[4];
    if ((threadIdx.x & 63) == 0) wsum[threadIdx.x >> 6] = v;
    __syncthreads();
    if (threadIdx.x == 0) {
        float t = wsum[0] + wsum[1] + wsum[2] + wsum[3];
        out[0] = 1.0f - t * inv_total;
    }
}

extern "C" void kernel_launch(void* const* d_in, const int* in_sizes, int n_in,
                              void* d_out, int out_size, void* d_ws, size_t ws_size,
                              hipStream_t stream) {
    const float* I = (const float*)d_in[0];   // predict
    const float* J = (const float*)d_in[1];   // target
    float* out = (float*)d_out;
    float* partials = (float*)d_ws;           // nblocks floats (8 KB)

    const int n = in_sizes[0];                // B*1*H*W
    const int B = n / (H * W);
    const int nblocks = B * NBANDS;

    ncc_main<<<nblocks, NTHREADS, 0, stream>>>(I, J, partials);
    ncc_finish<<<1, 256, 0, stream>>>(partials, out, nblocks, 1.0f / (float)n);
}